// Round 7
// baseline (253.783 us; speedup 1.0000x reference)
//
#include <hip/hip_runtime.h>

// MHA forward, B=2, S=2048, D=1024, H=16, Dk=64, causal, RoPE. fp32 I/O.
// Internal bf16 MFMA 16x16x32, fp32 accum.
// R11: RoPE table. R12/R13 un-paired attn: FALSIFIED (spills / dispatch
// imbalance). R14 phase-fused dual proc: NEUTRAL. R15 in-register P via
// swapped QK + cvt_pk + bpermute: NEUTRAL (72us invariant across 3
// structures) -> limiter is 2 waves/SIMD exposing every latency.
// R17: 512-thread attn blocks, waves 0-3 tile qtA / 4-7 tile qtB, balanced
// 17-iter schedule. Occupancy doubled (36%) as designed BUT
// __launch_bounds__(512,4) forced VGPR=64 -> spills (WRITE 8->13.3MB),
// 87us. TWICE-MEASURED LAW (R12, R17): never force occupancy via the
// 2nd launch-bounds arg; relax and let actual VGPR (<=128) give 4
// waves/SIMD. R18: same structure, bound (512,2).

typedef unsigned short u16;
typedef __attribute__((ext_vector_type(8))) short short8;   // 8 bf16 = 4 VGPRs
typedef __attribute__((ext_vector_type(4))) float float4v;  // MFMA C/D

typedef const __attribute__((address_space(1))) void GV;    // global
typedef __attribute__((address_space(3))) void LV;          // LDS

#define VSTR 72   // attn Vt row stride (u16): 144B rows, 2-way read banks
#define QSCL 0.18033688011112042f   // 0.125 * log2(e)

__device__ __forceinline__ u16 f2b(float f) {
    union { float f; unsigned int i; } t; t.f = f;
    unsigned int r = t.i + 0x7fffu + ((t.i >> 16) & 1u);   // RNE
    return (u16)(r >> 16);
}

// ---------------- fused fp32 -> bf16 converter ------------------------------
__global__ __launch_bounds__(256) void cvt_all(
    const float4* __restrict__ x,  const float4* __restrict__ wq,
    const float4* __restrict__ wk, const float4* __restrict__ wv,
    const float4* __restrict__ wo,
    u16* __restrict__ xb, u16* __restrict__ wcat, u16* __restrict__ wob)
{
    const int i = blockIdx.x * 256 + threadIdx.x;
    const float4* s; u16* d; int off;
    if (i < 524288) { s = x; d = xb; off = i; }
    else {
        const int widx = i - 524288;
        const int w = widx >> 17, o = widx & 131071;
        switch (w) {
            case 0:  s = wq; d = wcat;              break;
            case 1:  s = wk; d = wcat + (1 << 20);  break;
            case 2:  s = wv; d = wcat + (2 << 20);  break;
            default: s = wo; d = wob;               break;
        }
        off = o;
    }
    float4 a = s[2 * off], b = s[2 * off + 1];
    u16 t[8] = {f2b(a.x), f2b(a.y), f2b(a.z), f2b(a.w),
                f2b(b.x), f2b(b.y), f2b(b.z), f2b(b.w)};
    reinterpret_cast<int4*>(d)[off] = *reinterpret_cast<int4*>(t);
}

// ---------------- RoPE cos/sin table: tab[pos*32+fi] = {cos, sin} ----------
__global__ __launch_bounds__(256) void rope_tab(float2* __restrict__ tab) {
    const int i = blockIdx.x * 256 + threadIdx.x;   // 0..65535
    const int pos = i >> 5, fi = i & 31;
    const float freq = exp2f((float)fi * -0.4152410118609203f);  // -log2(1e4)/32
    float sn, cs; sincosf((float)pos * freq, &sn, &cs);
    tab[i] = make_float2(cs, sn);
}

// ---------------------------------------------------------------------------
// Y[m][n] = sum_k X[m][k] * W[n][k]; 128(m) x NT*32(n) x 64(k) tiles.
// Staging: global_load_lds width=16. LDS: 64-elem rows, 16B unit u stored at
// phys u^(row&7) (lane-contiguous DMA dest, swizzled ds_read_b128).
// ROPE=1: route cols to Yq/Yk/Yv, RoPE q,k via table, scale q by QSCL.
// XCD swizzle: block g -> xcd=g&7 owns m-strips [xcd*4, xcd*4+4).
// ---------------------------------------------------------------------------
template<int NT, int ROPE, int NBLK>
__global__ __launch_bounds__(256) void gemm_tile(
    const u16* __restrict__ X, const u16* __restrict__ Wb,
    u16* __restrict__ Yq, u16* __restrict__ Yk, u16* __restrict__ Yv,
    float* __restrict__ Yf, const float2* __restrict__ tab)
{
    __shared__ u16 As[128 * 64];
    __shared__ u16 Bs[NT * 32 * 64];

    const int tid  = threadIdx.x;
    const int wave = tid >> 6;
    const int lane = tid & 63;
    const int quad = lane >> 4;
    const int l16  = lane & 15;
    const int wm = (wave >> 1) * 64, wn = (wave & 1) * (NT * 16);
    const int g = blockIdx.x;
    const int rr = g >> 3;
    const int m0 = ((g & 7) * 4 + rr / NBLK) * 128;
    const int n0 = (rr % NBLK) * (NT * 32);
    const int lrow = lane >> 3;                         // 0..7 within 8-row slab
    const int cg8  = (lane & 7) ^ lrow;                 // swizzled global unit

    float4v acc[4][NT];
#pragma unroll
    for (int mt = 0; mt < 4; mt++)
#pragma unroll
        for (int nt = 0; nt < NT; nt++) acc[mt][nt] = (float4v){0.f, 0.f, 0.f, 0.f};

    for (int kb = 0; kb < 1024; kb += 64) {
        __syncthreads();                                 // prev reads done
#pragma unroll
        for (int t = 0; t < 4; t++) {                    // stage A: 4x 1KB/wave
            const int I = wave * 4 + t;
            const u16* gp = X + (size_t)(m0 + I * 8 + lrow) * 1024 + kb + cg8 * 8;
            __builtin_amdgcn_global_load_lds((GV*)gp, (LV*)&As[I * 512], 16, 0, 0);
        }
#pragma unroll
        for (int t = 0; t < NT; t++) {                   // stage B: NTx 1KB/wave
            const int I = wave * NT + t;
            const u16* gp = Wb + (size_t)(n0 + I * 8 + lrow) * 1024 + kb + cg8 * 8;
            __builtin_amdgcn_global_load_lds((GV*)gp, (LV*)&Bs[I * 512], 16, 0, 0);
        }
        __syncthreads();                                 // vmcnt drained here
#pragma unroll
        for (int ks = 0; ks < 2; ks++) {
            const int su = ((ks * 4 + quad) ^ (l16 & 7)) * 8;   // swizzled unit
            short8 af[4], bf[NT];
#pragma unroll
            for (int t = 0; t < 4; t++)
                af[t] = *reinterpret_cast<const short8*>(&As[(wm + t * 16 + l16) * 64 + su]);
#pragma unroll
            for (int t = 0; t < NT; t++)
                bf[t] = *reinterpret_cast<const short8*>(&Bs[(wn + t * 16 + l16) * 64 + su]);
#pragma unroll
            for (int mt = 0; mt < 4; mt++)
#pragma unroll
                for (int nt = 0; nt < NT; nt++)
                    acc[mt][nt] = __builtin_amdgcn_mfma_f32_16x16x32_bf16(af[mt], bf[nt], acc[mt][nt], 0, 0, 0);
        }
    }

    if (ROPE) {
#pragma unroll
        for (int nt = 0; nt < NT; nt++) {
            const int cg = n0 + wn + nt * 16 + l16;      // global col 0..3071
            const int buf = cg >> 10;                    // 0=q 1=k 2=v
            const int c = cg & 1023;
            u16* dst = (buf == 0) ? Yq : ((buf == 1) ? Yk : Yv);
            const bool rp = (buf < 2);
            const float scl = (buf == 0) ? QSCL : 1.0f;
            const int fi = (cg & 63) >> 1;               // pair index in head
#pragma unroll
            for (int mt = 0; mt < 4; mt++)
#pragma unroll
                for (int r = 0; r < 4; r++) {
                    const int row = m0 + wm + mt * 16 + quad * 4 + r;
                    float v = acc[mt][nt][r];
                    if (rp) {
                        const float2 t = tab[((row & 2047) << 5) + fi];
                        const float partner = __shfl_xor(v, 1);
                        v = (l16 & 1) ? fmaf(v, t.x,  partner * t.y)
                                      : fmaf(v, t.x, -partner * t.y);
                    }
                    dst[(size_t)row * 1024 + c] = f2b(v * scl);
                }
        }
    } else {
#pragma unroll
        for (int nt = 0; nt < NT; nt++) {
            const int col = n0 + wn + nt * 16 + l16;
#pragma unroll
            for (int mt = 0; mt < 4; mt++)
#pragma unroll
                for (int r = 0; r < 4; r++) {
                    const int row = m0 + wm + mt * 16 + quad * 4 + r;
                    Yf[(size_t)row * 1024 + col] = acc[mt][nt][r];
                }
        }
    }
}

// ---------------------------------------------------------------------------
// Flash causal attention, 512 threads (8 waves), 512 equal-work blocks.
// Waves 0-3 (grp A): q-tile qtA; waves 4-7 (grp B): q-tile qtB=31-qtA.
// Balanced schedule (17 iters): grpA KV tiles 0..16 (target A for i<=qtA,
// then target B); grpB KV tiles 0..qtA then 17..qtB (idle <=1 iter).
// Swapped QK^T (R15): P in-register, cvt_pk + bpermute redistribution.
// Unnormalized softmax (q pre-scaled 0.125*log2e, p=exp2f). Two Vt LDS
// buffers; K loaded per-iter before the staging barriers. Tile A written
// at the switch; tile B merged (A-partial + B-partial) via LDS. O aliases
// Q (each block owns its two tiles' rows exclusively). Bound (512,2):
// VGPR cap 256, allocator free; actual <=128 -> 4 waves/SIMD (R12/R17 law).
// ---------------------------------------------------------------------------
__global__ __launch_bounds__(512, 2) void attn_kernel(
    const u16* Q, const u16* __restrict__ K,
    const u16* __restrict__ V, u16* O)
{
    __shared__ union {
        u16 vt[2][64 * VSTR];                         // 2 x 9216 B
        struct { float o[4][64][17]; float s[4][64]; } m;  // 18432 B
    } sm;

    const int tid  = threadIdx.x;
    const int wave = tid >> 6;          // 0..7
    const int grp  = wave >> 2;         // 0 = tiles-A waves, 1 = tiles-B waves
    const int w4   = wave & 3;
    const int lane = tid & 63;
    const int quad = lane >> 4;
    const int l16  = lane & 15;
    const int g = blockIdx.x;
    const int xcd = g & 7, slot = g >> 3;
    const int G = (slot >> 4) * 8 + xcd;    // 0..31 = (b,h) group
    const int qtA = slot & 15;              // 0..15
    const int qtB = 31 - qtA;               // 31..16
    const int b = G & 1, h = G >> 1;
    const size_t base = ((size_t)b * 2048) * 1024 + (size_t)h * 64;

    int myqt = grp ? qtB : qtA;
    short8 qf[2];
    {
        const size_t r = base + (size_t)(myqt * 64 + w4 * 16 + l16) * 1024;
        qf[0] = *reinterpret_cast<const short8*>(Q + r + quad * 8);
        qf[1] = *reinterpret_cast<const short8*>(Q + r + 32 + quad * 8);
    }

    float4v o[4];
#pragma unroll
    for (int i = 0; i < 4; i++) o[i] = (float4v){0.f,0.f,0.f,0.f};
    float s = 0.f;

    // V staging coords (512 threads: 8 u16 each per buffer)
    const int srow = tid >> 3;             // 0..63
    const int c0   = (tid & 7) << 3;       // 0,8,...,56
    const int sxw  = srow ^ ((c0 >> 4) << 4);   // swizzled s for d in [c0,c0+8)

    const u16* Vbase = V + base + (size_t)srow * 1024 + c0;
    const u16* kbase = K + base + (size_t)l16 * 1024 + quad * 8;
    int4 vrA = *reinterpret_cast<const int4*>(Vbase);   // tile 0
    int4 vrB;                                           // valid from i=qtA+1

    // bpermute byte-addrs: src lane = ((quad&1)*2 + (j>>1))*16 + l16
    const int bpa0 = (((quad & 1) * 2) * 16 + l16) * 4;
    const int bpa1 = bpa0 + 64;
    const bool hiq = quad >= 2;
    const int qloc = w4 * 16 + l16;        // lane's q-row within its tile

    for (int i = 0; i <= 16; ++i) {
        const int tb = (i <= qtA) ? i : i + 16 - qtA;   // grp-B KV tile

        if (grp == 0 && i == qtA + 1) {    // finalize tile A, switch to B
            float t = s;
            t += __shfl_xor(t, 16); t += __shfl_xor(t, 32);
#pragma unroll
            for (int r = 0; r < 4; r++) {
                const int rl = quad * 4 + r;
                const float inv = 1.0f / __shfl(t, rl);
                const size_t row = base + (size_t)(qtA * 64 + w4 * 16 + rl) * 1024;
#pragma unroll
                for (int dt = 0; dt < 4; dt++)
                    O[row + dt * 16 + l16] = f2b(o[dt][r] * inv);
            }
#pragma unroll
            for (int k = 0; k < 4; k++) o[k] = (float4v){0.f,0.f,0.f,0.f};
            s = 0.f;
            myqt = qtB;
            const size_t r = base + (size_t)(qtB * 64 + w4 * 16 + l16) * 1024;
            qf[0] = *reinterpret_cast<const short8*>(Q + r + quad * 8);
            qf[1] = *reinterpret_cast<const short8*>(Q + r + 32 + quad * 8);
        }

        const int mytile = grp ? tb : i;
        const bool active = (grp == 0) || (tb <= qtB);

        short8 kc[4][2];                   // K frags: issue before barriers
        if (active) {
            const u16* kp = kbase + (size_t)mytile * 65536;
#pragma unroll
            for (int nt = 0; nt < 4; nt++)
#pragma unroll
                for (int ks = 0; ks < 2; ks++)
                    kc[nt][ks] = *reinterpret_cast<const short8*>(kp + (size_t)(nt * 16) * 1024 + ks * 32);
        }

        __syncthreads();                   // all waves done with prev Vt
        {
            const u16* a = reinterpret_cast<const u16*>(&vrA);
#pragma unroll
            for (int e = 0; e < 8; e++) sm.vt[0][(c0 + e) * VSTR + sxw] = a[e];
        }
        if (i > qtA && tb <= qtB) {
            const u16* a = reinterpret_cast<const u16*>(&vrB);
#pragma unroll
            for (int e = 0; e < 8; e++) sm.vt[1][(c0 + e) * VSTR + sxw] = a[e];
        }
        __syncthreads();

        if (i < 16) {                      // prefetch next-iter V tiles
            vrA = *reinterpret_cast<const int4*>(Vbase + (size_t)(i + 1) * 65536);
            if (i + 1 > qtA) {
                const int tbn = i + 17 - qtA;
                if (tbn <= qtB)
                    vrB = *reinterpret_cast<const int4*>(Vbase + (size_t)tbn * 65536);
            }
        }

        if (active) {
            const u16* Vt = sm.vt[(grp && i > qtA) ? 1 : 0];
            // QK (swapped): sacc[nt][r] = S[q=qloc][k=nt*16+quad*4+r]
            float4v sacc[4];
#pragma unroll
            for (int nt = 0; nt < 4; nt++) {
                sacc[nt] = (float4v){0.f, 0.f, 0.f, 0.f};
#pragma unroll
                for (int ks = 0; ks < 2; ks++)
                    sacc[nt] = __builtin_amdgcn_mfma_f32_16x16x32_bf16(kc[nt][ks], qf[ks], sacc[nt], 0, 0, 0);
            }
            // softmax + pack + quad exchange
            const bool diag = (mytile == myqt);
            unsigned int w[4][2];
#pragma unroll
            for (int nt = 0; nt < 4; nt++) {
                float p[4];
#pragma unroll
                for (int r = 0; r < 4; r++) {
                    float sv = sacc[nt][r];                      // log2-domain
                    if (diag && (nt * 16 + quad * 4 + r > qloc)) sv = -1e30f;
                    p[r] = exp2f(sv);
                    s += p[r];
                }
                asm("v_cvt_pk_bf16_f32 %0, %1, %2" : "=v"(w[nt][0]) : "v"(p[0]), "v"(p[1]));
                asm("v_cvt_pk_bf16_f32 %0, %1, %2" : "=v"(w[nt][1]) : "v"(p[2]), "v"(p[3]));
            }
            short8 pa[2];
#pragma unroll
            for (int ks = 0; ks < 2; ks++) {
                unsigned int pw[4];
#pragma unroll
                for (int j = 0; j < 4; j++) {
                    const int addr = (j >> 1) ? bpa1 : bpa0;
                    const int rp = j & 1;
                    int lo_ = __builtin_amdgcn_ds_bpermute(addr, (int)w[2 * ks][rp]);
                    int hi_ = __builtin_amdgcn_ds_bpermute(addr, (int)w[2 * ks + 1][rp]);
                    pw[j] = (unsigned int)(hiq ? hi_ : lo_);
                }
                union { unsigned int u[4]; short8 s8; } t;
                t.u[0] = pw[0]; t.u[1] = pw[1]; t.u[2] = pw[2]; t.u[3] = pw[3];
                pa[ks] = t.s8;
            }
            // PV: vf loaded per-ks (16 VGPR live instead of 32)
#pragma unroll
            for (int ks = 0; ks < 2; ks++) {
                short8 vfk[4];
#pragma unroll
                for (int dt = 0; dt < 4; dt++)
                    vfk[dt] = *reinterpret_cast<const short8*>(&Vt[(dt * 16 + l16) * VSTR + ((ks * 32 + quad * 8) ^ (dt << 4))]);
#pragma unroll
                for (int dt = 0; dt < 4; dt++)
                    o[dt] = __builtin_amdgcn_mfma_f32_16x16x32_bf16(pa[ks], vfk[dt], o[dt], 0, 0, 0);
            }
        }
    }

    // epilogue: merge tile-B partials (grpA holds tiles qtA+1..16 part)
    __syncthreads();
    if (grp == 0) {
#pragma unroll
        for (int dt = 0; dt < 4; dt++)
#pragma unroll
            for (int r = 0; r < 4; r++) sm.m.o[w4][lane][dt * 4 + r] = o[dt][r];
        sm.m.s[w4][lane] = s;
    }
    __syncthreads();
    if (grp == 1) {
        float t = s + sm.m.s[w4][lane];
#pragma unroll
        for (int dt = 0; dt < 4; dt++)
#pragma unroll
            for (int r = 0; r < 4; r++) o[dt][r] += sm.m.o[w4][lane][dt * 4 + r];
        t += __shfl_xor(t, 16); t += __shfl_xor(t, 32);
#pragma unroll
        for (int r = 0; r < 4; r++) {
            const int rl = quad * 4 + r;
            const float inv = 1.0f / __shfl(t, rl);
            const size_t row = base + (size_t)(qtB * 64 + w4 * 16 + rl) * 1024;
#pragma unroll
            for (int dt = 0; dt < 4; dt++)
                O[row + dt * 16 + l16] = f2b(o[dt][r] * inv);
        }
    }
}

// ---------------------------------------------------------------------------
extern "C" void kernel_launch(void* const* d_in, const int* in_sizes, int n_in,
                              void* d_out, int out_size, void* d_ws, size_t ws_size,
                              hipStream_t stream) {
    (void)in_sizes; (void)n_in; (void)out_size; (void)ws_size;
    const float* x  = (const float*)d_in[0];
    const float* wq = (const float*)d_in[1];
    const float* wk = (const float*)d_in[2];
    const float* wv = (const float*)d_in[3];
    const float* wo = (const float*)d_in[4];

    const size_t MN = (size_t)4096 * 1024;

    // d_out (16MB): xb (8MB) + wcat (6MB) + rope table (512KB in free tail);
    // all consumed before the final fp32 GEMM overwrites d_out.
    u16* xb   = (u16*)d_out;
    u16* wcat = xb + MN;                    // [3072][1024] = wq|wk|wv rows
    float2* tab = (float2*)(wcat + (size_t)3072 * 1024);
    u16* qbuf = (u16*)d_ws;                 // also attention output
    u16* kbuf = qbuf + MN;
    u16* vbuf = kbuf + MN;
    u16* wob  = vbuf + MN;                  // ws total: 26MB

    cvt_all<<<4096, 256, 0, stream>>>((const float4*)x, (const float4*)wq,
                                      (const float4*)wk, (const float4*)wv,
                                      (const float4*)wo, xb, wcat, wob);
    rope_tab<<<256, 256, 0, stream>>>(tab);
    gemm_tile<4, 1, 24><<<768, 256, 0, stream>>>(xb, wcat, qbuf, kbuf, vbuf, nullptr, tab);
    attn_kernel<<<512, 512, 0, stream>>>(qbuf, kbuf, vbuf, qbuf);
    gemm_tile<2, 0, 16><<<512, 256, 0, stream>>>(qbuf, wob, nullptr, nullptr, nullptr, (float*)d_out, nullptr);
}

// Round 8
// 229.451 us; speedup vs baseline: 1.1060x; 1.1060x over previous
//
#include <hip/hip_runtime.h>

// MHA forward, B=2, S=2048, D=1024, H=16, Dk=64, causal, RoPE. fp32 I/O.
// Internal bf16 MFMA 16x16x32, fp32 accum.
// R11: RoPE table. R12/R13 un-paired attn: FALSIFIED (spills / dispatch
// imbalance). R14 phase-fused dual proc: NEUTRAL. R15 swapped-QK in-reg P
// via cvt_pk + bpermute: NEUTRAL (bpermute latency == deleted LDS trip).
// R17/R18 512-thread blocks: FALSIFIED both ways (forced bound -> spills;
// relaxed -> 8-wave barrier convoy, 96us). Base = R15 256-thread (72us).
// R19: (a) sigma-permuted PV: MFMA contracts A-slot p vs B-slot p, so any
// k-bijection applied to BOTH operands is identity. Pick sigma = QK output
// order k(e)=ks*32+(e>>2)*16+quad*4+(e&3): pa[ks] = own packed words
// (w[2ks][0],w[2ks][1],w[2ks+1][0],w[2ks+1][1]) -- ALL 16 bpermutes + 8
// selects deleted; vf becomes 2 x ds_read_b64 at k-offs (ks*32+quad*4)
// ^(dt<<4) and +16 (same bytes, same 2-way banks). (b) double-buffered Vt
// -> ONE __syncthreads per iteration (top barrier protects the buffer
// being restaged; stage and compute touch different buffers).

typedef unsigned short u16;
typedef __attribute__((ext_vector_type(8))) short short8;   // 8 bf16 = 4 VGPRs
typedef __attribute__((ext_vector_type(4))) float float4v;  // MFMA C/D

typedef const __attribute__((address_space(1))) void GV;    // global
typedef __attribute__((address_space(3))) void LV;          // LDS

#define VSTR 72   // attn Vt row stride (u16): 144B rows, 2-way read banks
#define QSCL 0.18033688011112042f   // 0.125 * log2(e)

__device__ __forceinline__ u16 f2b(float f) {
    union { float f; unsigned int i; } t; t.f = f;
    unsigned int r = t.i + 0x7fffu + ((t.i >> 16) & 1u);   // RNE
    return (u16)(r >> 16);
}

// ---------------- fused fp32 -> bf16 converter ------------------------------
__global__ __launch_bounds__(256) void cvt_all(
    const float4* __restrict__ x,  const float4* __restrict__ wq,
    const float4* __restrict__ wk, const float4* __restrict__ wv,
    const float4* __restrict__ wo,
    u16* __restrict__ xb, u16* __restrict__ wcat, u16* __restrict__ wob)
{
    const int i = blockIdx.x * 256 + threadIdx.x;
    const float4* s; u16* d; int off;
    if (i < 524288) { s = x; d = xb; off = i; }
    else {
        const int widx = i - 524288;
        const int w = widx >> 17, o = widx & 131071;
        switch (w) {
            case 0:  s = wq; d = wcat;              break;
            case 1:  s = wk; d = wcat + (1 << 20);  break;
            case 2:  s = wv; d = wcat + (2 << 20);  break;
            default: s = wo; d = wob;               break;
        }
        off = o;
    }
    float4 a = s[2 * off], b = s[2 * off + 1];
    u16 t[8] = {f2b(a.x), f2b(a.y), f2b(a.z), f2b(a.w),
                f2b(b.x), f2b(b.y), f2b(b.z), f2b(b.w)};
    reinterpret_cast<int4*>(d)[off] = *reinterpret_cast<int4*>(t);
}

// ---------------- RoPE cos/sin table: tab[pos*32+fi] = {cos, sin} ----------
__global__ __launch_bounds__(256) void rope_tab(float2* __restrict__ tab) {
    const int i = blockIdx.x * 256 + threadIdx.x;   // 0..65535
    const int pos = i >> 5, fi = i & 31;
    const float freq = exp2f((float)fi * -0.4152410118609203f);  // -log2(1e4)/32
    float sn, cs; sincosf((float)pos * freq, &sn, &cs);
    tab[i] = make_float2(cs, sn);
}

// ---------------------------------------------------------------------------
// Y[m][n] = sum_k X[m][k] * W[n][k]; 128(m) x NT*32(n) x 64(k) tiles.
// Staging: global_load_lds width=16. LDS: 64-elem rows, 16B unit u stored at
// phys u^(row&7) (lane-contiguous DMA dest, swizzled ds_read_b128).
// ROPE=1: route cols to Yq/Yk/Yv, RoPE q,k via table, scale q by QSCL.
// XCD swizzle: block g -> xcd=g&7 owns m-strips [xcd*4, xcd*4+4).
// ---------------------------------------------------------------------------
template<int NT, int ROPE, int NBLK>
__global__ __launch_bounds__(256) void gemm_tile(
    const u16* __restrict__ X, const u16* __restrict__ Wb,
    u16* __restrict__ Yq, u16* __restrict__ Yk, u16* __restrict__ Yv,
    float* __restrict__ Yf, const float2* __restrict__ tab)
{
    __shared__ u16 As[128 * 64];
    __shared__ u16 Bs[NT * 32 * 64];

    const int tid  = threadIdx.x;
    const int wave = tid >> 6;
    const int lane = tid & 63;
    const int quad = lane >> 4;
    const int l16  = lane & 15;
    const int wm = (wave >> 1) * 64, wn = (wave & 1) * (NT * 16);
    const int g = blockIdx.x;
    const int rr = g >> 3;
    const int m0 = ((g & 7) * 4 + rr / NBLK) * 128;
    const int n0 = (rr % NBLK) * (NT * 32);
    const int lrow = lane >> 3;                         // 0..7 within 8-row slab
    const int cg8  = (lane & 7) ^ lrow;                 // swizzled global unit

    float4v acc[4][NT];
#pragma unroll
    for (int mt = 0; mt < 4; mt++)
#pragma unroll
        for (int nt = 0; nt < NT; nt++) acc[mt][nt] = (float4v){0.f, 0.f, 0.f, 0.f};

    for (int kb = 0; kb < 1024; kb += 64) {
        __syncthreads();                                 // prev reads done
#pragma unroll
        for (int t = 0; t < 4; t++) {                    // stage A: 4x 1KB/wave
            const int I = wave * 4 + t;
            const u16* gp = X + (size_t)(m0 + I * 8 + lrow) * 1024 + kb + cg8 * 8;
            __builtin_amdgcn_global_load_lds((GV*)gp, (LV*)&As[I * 512], 16, 0, 0);
        }
#pragma unroll
        for (int t = 0; t < NT; t++) {                   // stage B: NTx 1KB/wave
            const int I = wave * NT + t;
            const u16* gp = Wb + (size_t)(n0 + I * 8 + lrow) * 1024 + kb + cg8 * 8;
            __builtin_amdgcn_global_load_lds((GV*)gp, (LV*)&Bs[I * 512], 16, 0, 0);
        }
        __syncthreads();                                 // vmcnt drained here
#pragma unroll
        for (int ks = 0; ks < 2; ks++) {
            const int su = ((ks * 4 + quad) ^ (l16 & 7)) * 8;   // swizzled unit
            short8 af[4], bf[NT];
#pragma unroll
            for (int t = 0; t < 4; t++)
                af[t] = *reinterpret_cast<const short8*>(&As[(wm + t * 16 + l16) * 64 + su]);
#pragma unroll
            for (int t = 0; t < NT; t++)
                bf[t] = *reinterpret_cast<const short8*>(&Bs[(wn + t * 16 + l16) * 64 + su]);
#pragma unroll
            for (int mt = 0; mt < 4; mt++)
#pragma unroll
                for (int nt = 0; nt < NT; nt++)
                    acc[mt][nt] = __builtin_amdgcn_mfma_f32_16x16x32_bf16(af[mt], bf[nt], acc[mt][nt], 0, 0, 0);
        }
    }

    if (ROPE) {
#pragma unroll
        for (int nt = 0; nt < NT; nt++) {
            const int cg = n0 + wn + nt * 16 + l16;      // global col 0..3071
            const int buf = cg >> 10;                    // 0=q 1=k 2=v
            const int c = cg & 1023;
            u16* dst = (buf == 0) ? Yq : ((buf == 1) ? Yk : Yv);
            const bool rp = (buf < 2);
            const float scl = (buf == 0) ? QSCL : 1.0f;
            const int fi = (cg & 63) >> 1;               // pair index in head
#pragma unroll
            for (int mt = 0; mt < 4; mt++)
#pragma unroll
                for (int r = 0; r < 4; r++) {
                    const int row = m0 + wm + mt * 16 + quad * 4 + r;
                    float v = acc[mt][nt][r];
                    if (rp) {
                        const float2 t = tab[((row & 2047) << 5) + fi];
                        const float partner = __shfl_xor(v, 1);
                        v = (l16 & 1) ? fmaf(v, t.x,  partner * t.y)
                                      : fmaf(v, t.x, -partner * t.y);
                    }
                    dst[(size_t)row * 1024 + c] = f2b(v * scl);
                }
        }
    } else {
#pragma unroll
        for (int nt = 0; nt < NT; nt++) {
            const int col = n0 + wn + nt * 16 + l16;
#pragma unroll
            for (int mt = 0; mt < 4; mt++)
#pragma unroll
                for (int r = 0; r < 4; r++) {
                    const int row = m0 + wm + mt * 16 + quad * 4 + r;
                    Yf[(size_t)row * 1024 + col] = acc[mt][nt][r];
                }
        }
    }
}

// ---------------------------------------------------------------------------
// Flash causal attention, paired q-tiles (qtA, 31-qtA) -> 512 equal-work
// blocks, 256 threads. Unnormalized softmax (q pre-scaled 0.125*log2e,
// p = exp2f(s)). Swapped QK^T: lane holds S[q=wave*16+l16][k=nt*16+quad*4+r].
// R19 sigma-PV: pa[ks] = packed own words (no cross-lane); vf = 2 x b64 at
// sigma'd k-offsets. Double-buffered Vt, ONE barrier/iter. K frags direct
// from global, prefetched. XCD grouping: 16 blocks of one (b,h) per XCD L2.
// O aliases Q.
// ---------------------------------------------------------------------------
__global__ __launch_bounds__(256, 2) void attn_kernel(
    const u16* Q, const u16* __restrict__ K,
    const u16* __restrict__ V, u16* O)
{
    __shared__ __align__(16) u16 Vt[2][64 * VSTR];   // Vt[b][d][s^((d>>4)<<4)]

    const int tid  = threadIdx.x;
    const int wave = tid >> 6;
    const int lane = tid & 63;
    const int quad = lane >> 4;
    const int l16  = lane & 15;
    const int g = blockIdx.x;
    const int xcd = g & 7, slot = g >> 3;
    const int G = (slot >> 4) * 8 + xcd;    // 0..31 = (b,h) group
    const int qtA = slot & 15;              // 0..15
    const int qtB = 31 - qtA;               // 31..16
    const int b = G & 1, h = G >> 1;
    const size_t base = ((size_t)b * 2048) * 1024 + (size_t)h * 64;

    short8 qfA[2], qfB[2];
    {
        const size_t ra = base + (size_t)(qtA * 64 + wave * 16 + l16) * 1024;
        qfA[0] = *reinterpret_cast<const short8*>(Q + ra + quad * 8);
        qfA[1] = *reinterpret_cast<const short8*>(Q + ra + 32 + quad * 8);
        const size_t rb = base + (size_t)(qtB * 64 + wave * 16 + l16) * 1024;
        qfB[0] = *reinterpret_cast<const short8*>(Q + rb + quad * 8);
        qfB[1] = *reinterpret_cast<const short8*>(Q + rb + 32 + quad * 8);
    }

    float4v oA[4], oB[4];
#pragma unroll
    for (int i = 0; i < 4; i++) { oA[i] = (float4v){0.f,0.f,0.f,0.f}; oB[i] = (float4v){0.f,0.f,0.f,0.f}; }
    float sA = 0.f, sB = 0.f;               // row-sum partial for q = wave*16+l16

    const int srow = tid >> 2;             // 0..63 (coalesced: 4 lanes/row)
    const int cb   = (tid & 3) << 4;       // 0,16,32,48
    const int sxw  = srow ^ cb;            // swizzled s ((d>>4)<<4 == cb)

    const u16* Vp = V + base + (size_t)srow * 1024 + cb;
    const u16* kbase = K + base + (size_t)l16 * 1024 + quad * 8;
    int4 vr0 = *reinterpret_cast<const int4*>(Vp);          // tile 0
    int4 vr1 = *reinterpret_cast<const int4*>(Vp + 8);
    short8 kn[4][2], kc[4][2], vf[4][2];
#pragma unroll
    for (int nt = 0; nt < 4; nt++)                          // K tile 0
#pragma unroll
        for (int ks = 0; ks < 2; ks++)
            kn[nt][ks] = *reinterpret_cast<const short8*>(kbase + (size_t)(nt * 16) * 1024 + ks * 32);

    // prologue: stage tile 0 -> Vt[0]; then vr <- tile 1 (qtB >= 16 always)
    {
        const u16* a = reinterpret_cast<const u16*>(&vr0);
        const u16* c = reinterpret_cast<const u16*>(&vr1);
#pragma unroll
        for (int e = 0; e < 8; e++) Vt[0][(cb + e) * VSTR + sxw] = a[e];
#pragma unroll
        for (int e = 0; e < 8; e++) Vt[0][(cb + 8 + e) * VSTR + sxw] = c[e];
    }
    vr0 = *reinterpret_cast<const int4*>(Vp + 65536);
    vr1 = *reinterpret_cast<const int4*>(Vp + 65536 + 8);

    const int qloc = wave * 16 + l16;      // this lane's q within the 64-tile

    // SWAPPED QK: sacc[nt][r] = S[q=qloc][k = nt*16 + quad*4 + r]
    auto qk = [&](const short8 (&qf)[2], float4v (&sacc)[4]) {
#pragma unroll
        for (int nt = 0; nt < 4; nt++) {
            sacc[nt] = (float4v){0.f, 0.f, 0.f, 0.f};
#pragma unroll
            for (int ks = 0; ks < 2; ks++)
                sacc[nt] = __builtin_amdgcn_mfma_f32_16x16x32_bf16(kc[nt][ks], qf[ks], sacc[nt], 0, 0, 0);
        }
    };
    // softmax + pack; sigma-PV: pa[ks] = (w[2ks][0], w[2ks][1], w[2ks+1][0],
    // w[2ks+1][1]) -- lane-local, zero cross-lane ops.
    auto smx = [&](const float4v (&sacc)[4], float &sr, short8 (&pa)[2], bool diag) {
        unsigned int w[4][2];
#pragma unroll
        for (int nt = 0; nt < 4; nt++) {
            float p[4];
#pragma unroll
            for (int r = 0; r < 4; r++) {
                float sv = sacc[nt][r];                      // log2-domain
                if (diag && (nt * 16 + quad * 4 + r > qloc)) sv = -1e30f;
                p[r] = exp2f(sv);                            // masked -> 0
                sr += p[r];
            }
            asm("v_cvt_pk_bf16_f32 %0, %1, %2" : "=v"(w[nt][0]) : "v"(p[0]), "v"(p[1]));
            asm("v_cvt_pk_bf16_f32 %0, %1, %2" : "=v"(w[nt][1]) : "v"(p[2]), "v"(p[3]));
        }
        union { unsigned int u[4]; short8 s8; } t;
        t.u[0] = w[0][0]; t.u[1] = w[0][1]; t.u[2] = w[1][0]; t.u[3] = w[1][1];
        pa[0] = t.s8;
        t.u[0] = w[2][0]; t.u[1] = w[2][1]; t.u[2] = w[3][0]; t.u[3] = w[3][1];
        pa[1] = t.s8;
    };
    auto pv = [&](const short8 (&pa)[2], float4v (&oc)[4]) {
#pragma unroll
        for (int ks = 0; ks < 2; ks++)
#pragma unroll
            for (int dt = 0; dt < 4; dt++)
                oc[dt] = __builtin_amdgcn_mfma_f32_16x16x32_bf16(pa[ks], vf[dt][ks], oc[dt], 0, 0, 0);
    };

    for (int j = 0; j <= qtB; j++) {
        __syncthreads();   // protects Vt[(j+1)&1]: its iter-(j-1) readers done
        if (j < qtB) {     // stage tile j+1 (in vr) -> Vt[(j+1)&1]
            u16* D = Vt[(j + 1) & 1];
            const u16* a = reinterpret_cast<const u16*>(&vr0);
            const u16* c = reinterpret_cast<const u16*>(&vr1);
#pragma unroll
            for (int e = 0; e < 8; e++) D[(cb + e) * VSTR + sxw] = a[e];
#pragma unroll
            for (int e = 0; e < 8; e++) D[(cb + 8 + e) * VSTR + sxw] = c[e];
        }
#pragma unroll
        for (int nt = 0; nt < 4; nt++)
#pragma unroll
            for (int ks = 0; ks < 2; ks++) kc[nt][ks] = kn[nt][ks];
        if (j < qtB) {     // prefetch: V tile j+2, K tile j+1
            if (j + 2 <= qtB) {
                vr0 = *reinterpret_cast<const int4*>(Vp + (size_t)(j + 2) * 65536);
                vr1 = *reinterpret_cast<const int4*>(Vp + (size_t)(j + 2) * 65536 + 8);
            }
            const u16* kb2 = kbase + (size_t)(j + 1) * 65536;
#pragma unroll
            for (int nt = 0; nt < 4; nt++)
#pragma unroll
                for (int ks = 0; ks < 2; ks++)
                    kn[nt][ks] = *reinterpret_cast<const short8*>(kb2 + (size_t)(nt * 16) * 1024 + ks * 32);
        }
        // vf from Vt[j&1], sigma'd k-order: elem e reads V[k(e)][d],
        // k(e) = ks*32 + (e>>2)*16 + quad*4 + (e&3); phys k ^= (d>>4)<<4.
        {
            const u16* B = Vt[j & 1];
#pragma unroll
            for (int dt = 0; dt < 4; dt++) {
                const int rb = (dt * 16 + l16) * VSTR;
#pragma unroll
                for (int ks = 0; ks < 2; ks++) {
                    const int k1 = (ks * 32 + quad * 4) ^ (dt << 4);
                    const int k2 = (ks * 32 + 16 + quad * 4) ^ (dt << 4);
                    union { struct { uint2 lo, hi; } p; short8 s8; } u;
                    u.p.lo = *reinterpret_cast<const uint2*>(&B[rb + k1]);
                    u.p.hi = *reinterpret_cast<const uint2*>(&B[rb + k2]);
                    vf[dt][ks] = u.s8;
                }
            }
        }

        if (j <= qtA) {    // dual proc
            float4v xA[4], xB[4];
            qk(qfA, xA);
            qk(qfB, xB);
            short8 paA[2], paB[2];
            smx(xA, sA, paA, j == qtA);
            smx(xB, sB, paB, false);     // qtB >= 16 > qtA >= j: never diag
            pv(paA, oA);
            pv(paB, oB);
        } else {           // tail: only B remains
            float4v xB[4];
            qk(qfB, xB);
            short8 paB[2];
            smx(xB, sB, paB, j == qtB);
            pv(paB, oB);
        }
    }

    // epilogue: quad-reduce row sums, redistribute via shfl, normalize, write
    float tA = sA, tB = sB;
    tA += __shfl_xor(tA, 16); tA += __shfl_xor(tA, 32);
    tB += __shfl_xor(tB, 16); tB += __shfl_xor(tB, 32);
#pragma unroll
    for (int r = 0; r < 4; r++) {
        const int rl = quad * 4 + r;                 // q-local of o[.][r]
        const float invA = 1.0f / __shfl(tA, rl);    // lane rl holds q=wave*16+rl
        const float invB = 1.0f / __shfl(tB, rl);
        const size_t rowA = base + (size_t)(qtA * 64 + wave * 16 + rl) * 1024;
        const size_t rowB = base + (size_t)(qtB * 64 + wave * 16 + rl) * 1024;
#pragma unroll
        for (int dt = 0; dt < 4; dt++) {
            O[rowA + dt * 16 + l16] = f2b(oA[dt][r] * invA);
            O[rowB + dt * 16 + l16] = f2b(oB[dt][r] * invB);
        }
    }
}

// ---------------------------------------------------------------------------
extern "C" void kernel_launch(void* const* d_in, const int* in_sizes, int n_in,
                              void* d_out, int out_size, void* d_ws, size_t ws_size,
                              hipStream_t stream) {
    (void)in_sizes; (void)n_in; (void)out_size; (void)ws_size;
    const float* x  = (const float*)d_in[0];
    const float* wq = (const float*)d_in[1];
    const float* wk = (const float*)d_in[2];
    const float* wv = (const float*)d_in[3];
    const float* wo = (const float*)d_in[4];

    const size_t MN = (size_t)4096 * 1024;

    // d_out (16MB): xb (8MB) + wcat (6MB) + rope table (512KB in free tail);
    // all consumed before the final fp32 GEMM overwrites d_out.
    u16* xb   = (u16*)d_out;
    u16* wcat = xb + MN;                    // [3072][1024] = wq|wk|wv rows
    float2* tab = (float2*)(wcat + (size_t)3072 * 1024);
    u16* qbuf = (u16*)d_ws;                 // also attention output
    u16* kbuf = qbuf + MN;
    u16* vbuf = kbuf + MN;
    u16* wob  = vbuf + MN;                  // ws total: 26MB

    cvt_all<<<4096, 256, 0, stream>>>((const float4*)x, (const float4*)wq,
                                      (const float4*)wk, (const float4*)wv,
                                      (const float4*)wo, xb, wcat, wob);
    rope_tab<<<256, 256, 0, stream>>>(tab);
    gemm_tile<4, 1, 24><<<768, 256, 0, stream>>>(xb, wcat, qbuf, kbuf, vbuf, nullptr, tab);
    attn_kernel<<<512, 256, 0, stream>>>(qbuf, kbuf, vbuf, qbuf);
    gemm_tile<2, 0, 16><<<512, 256, 0, stream>>>(qbuf, wob, nullptr, nullptr, nullptr, (float*)d_out, nullptr);
}

// Round 9
// 217.369 us; speedup vs baseline: 1.1675x; 1.0556x over previous
//
#include <hip/hip_runtime.h>

// MHA forward, B=2, S=2048, D=1024, H=16, Dk=64, causal, RoPE. fp32 I/O.
// Internal bf16 MFMA 16x16x32, fp32 accum.
// R11: RoPE table. R12/R13 un-paired attn: FALSIFIED (spills / dispatch
// imbalance). R14 phase-fused / R15 in-reg-P / R19 sigma-PV: all NEUTRAL --
// attn pinned at 72+-1us across SIX inner-loop structures (limiter is the
// 2-waves/SIMD latency exposure, not instruction mix). attn frozen at R19.
// R17/R18 512-thread attn: FALSIFIED (spills / 8-wave barrier convoy).
// R20: attack shifts to QKV GEMM (~60-70us by subtraction; never in top-5
// so <71us). New gemm_qkv: 256x192 tile -> grid 16x16=256 blocks = exactly
// 1/CU (256^2 would idle 25% of CUs), 8 waves (2mx4n), acc[8][3],
// double-buffered LDS (112KB) with T3-minimum 2-phase schedule: stage
// K-step kb+1 into buf^1 BEFORE computing buf, ONE drain+barrier per step
// (learn_hip m230/m248: 655-735 TF in this exact 1-block/CU regime).
// Same slab swizzle as before (row&7==l16&7 holds: 48,128 multiples of 8).
// Proj GEMM and everything else unchanged.

typedef unsigned short u16;
typedef __attribute__((ext_vector_type(8))) short short8;   // 8 bf16 = 4 VGPRs
typedef __attribute__((ext_vector_type(4))) float float4v;  // MFMA C/D

typedef const __attribute__((address_space(1))) void GV;    // global
typedef __attribute__((address_space(3))) void LV;          // LDS

#define VSTR 72   // attn Vt row stride (u16): 144B rows, 2-way read banks
#define QSCL 0.18033688011112042f   // 0.125 * log2(e)

__device__ __forceinline__ u16 f2b(float f) {
    union { float f; unsigned int i; } t; t.f = f;
    unsigned int r = t.i + 0x7fffu + ((t.i >> 16) & 1u);   // RNE
    return (u16)(r >> 16);
}

// ---------------- fused fp32 -> bf16 converter ------------------------------
__global__ __launch_bounds__(256) void cvt_all(
    const float4* __restrict__ x,  const float4* __restrict__ wq,
    const float4* __restrict__ wk, const float4* __restrict__ wv,
    const float4* __restrict__ wo,
    u16* __restrict__ xb, u16* __restrict__ wcat, u16* __restrict__ wob)
{
    const int i = blockIdx.x * 256 + threadIdx.x;
    const float4* s; u16* d; int off;
    if (i < 524288) { s = x; d = xb; off = i; }
    else {
        const int widx = i - 524288;
        const int w = widx >> 17, o = widx & 131071;
        switch (w) {
            case 0:  s = wq; d = wcat;              break;
            case 1:  s = wk; d = wcat + (1 << 20);  break;
            case 2:  s = wv; d = wcat + (2 << 20);  break;
            default: s = wo; d = wob;               break;
        }
        off = o;
    }
    float4 a = s[2 * off], b = s[2 * off + 1];
    u16 t[8] = {f2b(a.x), f2b(a.y), f2b(a.z), f2b(a.w),
                f2b(b.x), f2b(b.y), f2b(b.z), f2b(b.w)};
    reinterpret_cast<int4*>(d)[off] = *reinterpret_cast<int4*>(t);
}

// ---------------- RoPE cos/sin table: tab[pos*32+fi] = {cos, sin} ----------
__global__ __launch_bounds__(256) void rope_tab(float2* __restrict__ tab) {
    const int i = blockIdx.x * 256 + threadIdx.x;   // 0..65535
    const int pos = i >> 5, fi = i & 31;
    const float freq = exp2f((float)fi * -0.4152410118609203f);  // -log2(1e4)/32
    float sn, cs; sincosf((float)pos * freq, &sn, &cs);
    tab[i] = make_float2(cs, sn);
}

// ---------------------------------------------------------------------------
// QKV GEMM: Y[m][n] = sum_k X[m][k] * W[n][k]; 256(m) x 192(n) x 64(k) steps.
// 512 threads, 8 waves (2m x 4n), per-wave 128x48 (acc[8][3]).
// Double-buffered LDS, 2-phase: stage(kb+1 -> buf^1) BEFORE compute(buf);
// one __syncthreads (full drain) per K-step. glds width=16; LDS slab
// swizzle: 16B unit u of row stored at phys u^(row&7), pre-swizzled global
// source cg8. Grid 256 = 16m x 16n, XCD-grouped: xcd g&7 owns 2 m-strips.
// Epilogue: route cols to Yq/Yk/Yv, RoPE q,k via table, scale q by QSCL.
// ---------------------------------------------------------------------------
__global__ __launch_bounds__(512) void gemm_qkv(
    const u16* __restrict__ X, const u16* __restrict__ Wb,
    u16* __restrict__ Yq, u16* __restrict__ Yk, u16* __restrict__ Yv,
    const float2* __restrict__ tab)
{
    __shared__ u16 As[2][256 * 64];   // 2 x 32KB
    __shared__ u16 Bs[2][192 * 64];   // 2 x 24KB  (112KB total -> 1 block/CU)

    const int tid  = threadIdx.x;
    const int wave = tid >> 6;                          // 0..7
    const int lane = tid & 63;
    const int quad = lane >> 4;
    const int l16  = lane & 15;
    const int wm = (wave >> 2) * 128;                   // 0,128
    const int wn = (wave & 3) * 48;                     // 0,48,96,144
    const int g = blockIdx.x;
    const int rr = g >> 3;                              // 0..31
    const int m0 = ((g & 7) * 2 + (rr >> 4)) * 256;     // 16 m-tiles
    const int n0 = (rr & 15) * 192;                     // 16 n-tiles
    const int lrow = lane >> 3;                         // 0..7 within 8-row slab
    const int cg8  = (lane & 7) ^ lrow;                 // swizzled global unit

    float4v acc[8][3];
#pragma unroll
    for (int mt = 0; mt < 8; mt++)
#pragma unroll
        for (int nt = 0; nt < 3; nt++) acc[mt][nt] = (float4v){0.f, 0.f, 0.f, 0.f};

    auto stage = [&](int bsel, int kb) {
#pragma unroll
        for (int t = 0; t < 4; t++) {                   // A: 32 slabs of 8 rows
            const int I = wave * 4 + t;
            const u16* gp = X + (size_t)(m0 + I * 8 + lrow) * 1024 + kb + cg8 * 8;
            __builtin_amdgcn_global_load_lds((GV*)gp, (LV*)&As[bsel][I * 512], 16, 0, 0);
        }
#pragma unroll
        for (int t = 0; t < 3; t++) {                   // B: 24 slabs of 8 rows
            const int I = wave * 3 + t;
            const u16* gp = Wb + (size_t)(n0 + I * 8 + lrow) * 1024 + kb + cg8 * 8;
            __builtin_amdgcn_global_load_lds((GV*)gp, (LV*)&Bs[bsel][I * 512], 16, 0, 0);
        }
    };

    stage(0, 0);
    __syncthreads();                                    // drain vmcnt (buf0 ready)

    for (int kbi = 0; kbi < 16; kbi++) {
        const int cur = kbi & 1;
        if (kbi < 15) stage(cur ^ 1, (kbi + 1) * 64);   // prefetch next K-step
#pragma unroll
        for (int ks = 0; ks < 2; ks++) {
            const int su = ((ks * 4 + quad) ^ (l16 & 7)) * 8;   // swizzled unit
            short8 af[8], bf[3];
#pragma unroll
            for (int t = 0; t < 8; t++)
                af[t] = *reinterpret_cast<const short8*>(&As[cur][(wm + t * 16 + l16) * 64 + su]);
#pragma unroll
            for (int t = 0; t < 3; t++)
                bf[t] = *reinterpret_cast<const short8*>(&Bs[cur][(wn + t * 16 + l16) * 64 + su]);
#pragma unroll
            for (int mt = 0; mt < 8; mt++)
#pragma unroll
                for (int nt = 0; nt < 3; nt++)
                    acc[mt][nt] = __builtin_amdgcn_mfma_f32_16x16x32_bf16(af[mt], bf[nt], acc[mt][nt], 0, 0, 0);
        }
        __syncthreads();   // drains vmcnt (next buf staged) + lgkm; flip
    }

    // RoPE epilogue (identical math; nt<3, mt<8)
#pragma unroll
    for (int nt = 0; nt < 3; nt++) {
        const int cg = n0 + wn + nt * 16 + l16;      // global col 0..3071
        const int buf = cg >> 10;                    // 0=q 1=k 2=v
        const int c = cg & 1023;
        u16* dst = (buf == 0) ? Yq : ((buf == 1) ? Yk : Yv);
        const bool rp = (buf < 2);
        const float scl = (buf == 0) ? QSCL : 1.0f;
        const int fi = (cg & 63) >> 1;               // pair index in head
#pragma unroll
        for (int mt = 0; mt < 8; mt++)
#pragma unroll
            for (int r = 0; r < 4; r++) {
                const int row = m0 + wm + mt * 16 + quad * 4 + r;
                float v = acc[mt][nt][r];
                if (rp) {
                    const float2 t = tab[((row & 2047) << 5) + fi];
                    const float partner = __shfl_xor(v, 1);
                    v = (l16 & 1) ? fmaf(v, t.x,  partner * t.y)
                                  : fmaf(v, t.x, -partner * t.y);
                }
                dst[(size_t)row * 1024 + c] = f2b(v * scl);
            }
    }
}

// ---------------------------------------------------------------------------
// Out-proj GEMM (unchanged m97-class structure): 128(m) x NT*32(n) x 64(k).
// ---------------------------------------------------------------------------
template<int NT, int NBLK>
__global__ __launch_bounds__(256) void gemm_tile(
    const u16* __restrict__ X, const u16* __restrict__ Wb,
    float* __restrict__ Yf)
{
    __shared__ u16 As[128 * 64];
    __shared__ u16 Bs[NT * 32 * 64];

    const int tid  = threadIdx.x;
    const int wave = tid >> 6;
    const int lane = tid & 63;
    const int quad = lane >> 4;
    const int l16  = lane & 15;
    const int wm = (wave >> 1) * 64, wn = (wave & 1) * (NT * 16);
    const int g = blockIdx.x;
    const int rr = g >> 3;
    const int m0 = ((g & 7) * 4 + rr / NBLK) * 128;
    const int n0 = (rr % NBLK) * (NT * 32);
    const int lrow = lane >> 3;                         // 0..7 within 8-row slab
    const int cg8  = (lane & 7) ^ lrow;                 // swizzled global unit

    float4v acc[4][NT];
#pragma unroll
    for (int mt = 0; mt < 4; mt++)
#pragma unroll
        for (int nt = 0; nt < NT; nt++) acc[mt][nt] = (float4v){0.f, 0.f, 0.f, 0.f};

    for (int kb = 0; kb < 1024; kb += 64) {
        __syncthreads();                                 // prev reads done
#pragma unroll
        for (int t = 0; t < 4; t++) {                    // stage A: 4x 1KB/wave
            const int I = wave * 4 + t;
            const u16* gp = X + (size_t)(m0 + I * 8 + lrow) * 1024 + kb + cg8 * 8;
            __builtin_amdgcn_global_load_lds((GV*)gp, (LV*)&As[I * 512], 16, 0, 0);
        }
#pragma unroll
        for (int t = 0; t < NT; t++) {                   // stage B: NTx 1KB/wave
            const int I = wave * NT + t;
            const u16* gp = Wb + (size_t)(n0 + I * 8 + lrow) * 1024 + kb + cg8 * 8;
            __builtin_amdgcn_global_load_lds((GV*)gp, (LV*)&Bs[I * 512], 16, 0, 0);
        }
        __syncthreads();                                 // vmcnt drained here
#pragma unroll
        for (int ks = 0; ks < 2; ks++) {
            const int su = ((ks * 4 + quad) ^ (l16 & 7)) * 8;   // swizzled unit
            short8 af[4], bf[NT];
#pragma unroll
            for (int t = 0; t < 4; t++)
                af[t] = *reinterpret_cast<const short8*>(&As[(wm + t * 16 + l16) * 64 + su]);
#pragma unroll
            for (int t = 0; t < NT; t++)
                bf[t] = *reinterpret_cast<const short8*>(&Bs[(wn + t * 16 + l16) * 64 + su]);
#pragma unroll
            for (int mt = 0; mt < 4; mt++)
#pragma unroll
                for (int nt = 0; nt < NT; nt++)
                    acc[mt][nt] = __builtin_amdgcn_mfma_f32_16x16x32_bf16(af[mt], bf[nt], acc[mt][nt], 0, 0, 0);
        }
    }

#pragma unroll
    for (int nt = 0; nt < NT; nt++) {
        const int col = n0 + wn + nt * 16 + l16;
#pragma unroll
        for (int mt = 0; mt < 4; mt++)
#pragma unroll
            for (int r = 0; r < 4; r++) {
                const int row = m0 + wm + mt * 16 + quad * 4 + r;
                Yf[(size_t)row * 1024 + col] = acc[mt][nt][r];
            }
    }
}

// ---------------------------------------------------------------------------
// Flash causal attention, paired q-tiles (qtA, 31-qtA) -> 512 equal-work
// blocks, 256 threads. Unnormalized softmax (q pre-scaled 0.125*log2e,
// p = exp2f(s)). Swapped QK^T: lane holds S[q=wave*16+l16][k=nt*16+quad*4+r].
// R19 sigma-PV: pa[ks] = packed own words (no cross-lane); vf = 2 x b64 at
// sigma'd k-offsets. Double-buffered Vt, ONE barrier/iter. K frags direct
// from global, prefetched. XCD grouping: 16 blocks of one (b,h) per XCD L2.
// O aliases Q.
// ---------------------------------------------------------------------------
__global__ __launch_bounds__(256, 2) void attn_kernel(
    const u16* Q, const u16* __restrict__ K,
    const u16* __restrict__ V, u16* O)
{
    __shared__ __align__(16) u16 Vt[2][64 * VSTR];   // Vt[b][d][s^((d>>4)<<4)]

    const int tid  = threadIdx.x;
    const int wave = tid >> 6;
    const int lane = tid & 63;
    const int quad = lane >> 4;
    const int l16  = lane & 15;
    const int g = blockIdx.x;
    const int xcd = g & 7, slot = g >> 3;
    const int G = (slot >> 4) * 8 + xcd;    // 0..31 = (b,h) group
    const int qtA = slot & 15;              // 0..15
    const int qtB = 31 - qtA;               // 31..16
    const int b = G & 1, h = G >> 1;
    const size_t base = ((size_t)b * 2048) * 1024 + (size_t)h * 64;

    short8 qfA[2], qfB[2];
    {
        const size_t ra = base + (size_t)(qtA * 64 + wave * 16 + l16) * 1024;
        qfA[0] = *reinterpret_cast<const short8*>(Q + ra + quad * 8);
        qfA[1] = *reinterpret_cast<const short8*>(Q + ra + 32 + quad * 8);
        const size_t rb = base + (size_t)(qtB * 64 + wave * 16 + l16) * 1024;
        qfB[0] = *reinterpret_cast<const short8*>(Q + rb + quad * 8);
        qfB[1] = *reinterpret_cast<const short8*>(Q + rb + 32 + quad * 8);
    }

    float4v oA[4], oB[4];
#pragma unroll
    for (int i = 0; i < 4; i++) { oA[i] = (float4v){0.f,0.f,0.f,0.f}; oB[i] = (float4v){0.f,0.f,0.f,0.f}; }
    float sA = 0.f, sB = 0.f;               // row-sum partial for q = wave*16+l16

    const int srow = tid >> 2;             // 0..63 (coalesced: 4 lanes/row)
    const int cb   = (tid & 3) << 4;       // 0,16,32,48
    const int sxw  = srow ^ cb;            // swizzled s ((d>>4)<<4 == cb)

    const u16* Vp = V + base + (size_t)srow * 1024 + cb;
    const u16* kbase = K + base + (size_t)l16 * 1024 + quad * 8;
    int4 vr0 = *reinterpret_cast<const int4*>(Vp);          // tile 0
    int4 vr1 = *reinterpret_cast<const int4*>(Vp + 8);
    short8 kn[4][2], kc[4][2], vf[4][2];
#pragma unroll
    for (int nt = 0; nt < 4; nt++)                          // K tile 0
#pragma unroll
        for (int ks = 0; ks < 2; ks++)
            kn[nt][ks] = *reinterpret_cast<const short8*>(kbase + (size_t)(nt * 16) * 1024 + ks * 32);

    // prologue: stage tile 0 -> Vt[0]; then vr <- tile 1 (qtB >= 16 always)
    {
        const u16* a = reinterpret_cast<const u16*>(&vr0);
        const u16* c = reinterpret_cast<const u16*>(&vr1);
#pragma unroll
        for (int e = 0; e < 8; e++) Vt[0][(cb + e) * VSTR + sxw] = a[e];
#pragma unroll
        for (int e = 0; e < 8; e++) Vt[0][(cb + 8 + e) * VSTR + sxw] = c[e];
    }
    vr0 = *reinterpret_cast<const int4*>(Vp + 65536);
    vr1 = *reinterpret_cast<const int4*>(Vp + 65536 + 8);

    const int qloc = wave * 16 + l16;      // this lane's q within the 64-tile

    // SWAPPED QK: sacc[nt][r] = S[q=qloc][k = nt*16 + quad*4 + r]
    auto qk = [&](const short8 (&qf)[2], float4v (&sacc)[4]) {
#pragma unroll
        for (int nt = 0; nt < 4; nt++) {
            sacc[nt] = (float4v){0.f, 0.f, 0.f, 0.f};
#pragma unroll
            for (int ks = 0; ks < 2; ks++)
                sacc[nt] = __builtin_amdgcn_mfma_f32_16x16x32_bf16(kc[nt][ks], qf[ks], sacc[nt], 0, 0, 0);
        }
    };
    // softmax + pack; sigma-PV: pa[ks] = (w[2ks][0], w[2ks][1], w[2ks+1][0],
    // w[2ks+1][1]) -- lane-local, zero cross-lane ops.
    auto smx = [&](const float4v (&sacc)[4], float &sr, short8 (&pa)[2], bool diag) {
        unsigned int w[4][2];
#pragma unroll
        for (int nt = 0; nt < 4; nt++) {
            float p[4];
#pragma unroll
            for (int r = 0; r < 4; r++) {
                float sv = sacc[nt][r];                      // log2-domain
                if (diag && (nt * 16 + quad * 4 + r > qloc)) sv = -1e30f;
                p[r] = exp2f(sv);                            // masked -> 0
                sr += p[r];
            }
            asm("v_cvt_pk_bf16_f32 %0, %1, %2" : "=v"(w[nt][0]) : "v"(p[0]), "v"(p[1]));
            asm("v_cvt_pk_bf16_f32 %0, %1, %2" : "=v"(w[nt][1]) : "v"(p[2]), "v"(p[3]));
        }
        union { unsigned int u[4]; short8 s8; } t;
        t.u[0] = w[0][0]; t.u[1] = w[0][1]; t.u[2] = w[1][0]; t.u[3] = w[1][1];
        pa[0] = t.s8;
        t.u[0] = w[2][0]; t.u[1] = w[2][1]; t.u[2] = w[3][0]; t.u[3] = w[3][1];
        pa[1] = t.s8;
    };
    auto pv = [&](const short8 (&pa)[2], float4v (&oc)[4]) {
#pragma unroll
        for (int ks = 0; ks < 2; ks++)
#pragma unroll
            for (int dt = 0; dt < 4; dt++)
                oc[dt] = __builtin_amdgcn_mfma_f32_16x16x32_bf16(pa[ks], vf[dt][ks], oc[dt], 0, 0, 0);
    };

    for (int j = 0; j <= qtB; j++) {
        __syncthreads();   // protects Vt[(j+1)&1]: its iter-(j-1) readers done
        if (j < qtB) {     // stage tile j+1 (in vr) -> Vt[(j+1)&1]
            u16* D = Vt[(j + 1) & 1];
            const u16* a = reinterpret_cast<const u16*>(&vr0);
            const u16* c = reinterpret_cast<const u16*>(&vr1);
#pragma unroll
            for (int e = 0; e < 8; e++) D[(cb + e) * VSTR + sxw] = a[e];
#pragma unroll
            for (int e = 0; e < 8; e++) D[(cb + 8 + e) * VSTR + sxw] = c[e];
        }
#pragma unroll
        for (int nt = 0; nt < 4; nt++)
#pragma unroll
            for (int ks = 0; ks < 2; ks++) kc[nt][ks] = kn[nt][ks];
        if (j < qtB) {     // prefetch: V tile j+2, K tile j+1
            if (j + 2 <= qtB) {
                vr0 = *reinterpret_cast<const int4*>(Vp + (size_t)(j + 2) * 65536);
                vr1 = *reinterpret_cast<const int4*>(Vp + (size_t)(j + 2) * 65536 + 8);
            }
            const u16* kb2 = kbase + (size_t)(j + 1) * 65536;
#pragma unroll
            for (int nt = 0; nt < 4; nt++)
#pragma unroll
                for (int ks = 0; ks < 2; ks++)
                    kn[nt][ks] = *reinterpret_cast<const short8*>(kb2 + (size_t)(nt * 16) * 1024 + ks * 32);
        }
        // vf from Vt[j&1], sigma'd k-order: elem e reads V[k(e)][d],
        // k(e) = ks*32 + (e>>2)*16 + quad*4 + (e&3); phys k ^= (d>>4)<<4.
        {
            const u16* B = Vt[j & 1];
#pragma unroll
            for (int dt = 0; dt < 4; dt++) {
                const int rb = (dt * 16 + l16) * VSTR;
#pragma unroll
                for (int ks = 0; ks < 2; ks++) {
                    const int k1 = (ks * 32 + quad * 4) ^ (dt << 4);
                    const int k2 = (ks * 32 + 16 + quad * 4) ^ (dt << 4);
                    union { struct { uint2 lo, hi; } p; short8 s8; } u;
                    u.p.lo = *reinterpret_cast<const uint2*>(&B[rb + k1]);
                    u.p.hi = *reinterpret_cast<const uint2*>(&B[rb + k2]);
                    vf[dt][ks] = u.s8;
                }
            }
        }

        if (j <= qtA) {    // dual proc
            float4v xA[4], xB[4];
            qk(qfA, xA);
            qk(qfB, xB);
            short8 paA[2], paB[2];
            smx(xA, sA, paA, j == qtA);
            smx(xB, sB, paB, false);     // qtB >= 16 > qtA >= j: never diag
            pv(paA, oA);
            pv(paB, oB);
        } else {           // tail: only B remains
            float4v xB[4];
            qk(qfB, xB);
            short8 paB[2];
            smx(xB, sB, paB, j == qtB);
            pv(paB, oB);
        }
    }

    // epilogue: quad-reduce row sums, redistribute via shfl, normalize, write
    float tA = sA, tB = sB;
    tA += __shfl_xor(tA, 16); tA += __shfl_xor(tA, 32);
    tB += __shfl_xor(tB, 16); tB += __shfl_xor(tB, 32);
#pragma unroll
    for (int r = 0; r < 4; r++) {
        const int rl = quad * 4 + r;                 // q-local of o[.][r]
        const float invA = 1.0f / __shfl(tA, rl);    // lane rl holds q=wave*16+rl
        const float invB = 1.0f / __shfl(tB, rl);
        const size_t rowA = base + (size_t)(qtA * 64 + wave * 16 + rl) * 1024;
        const size_t rowB = base + (size_t)(qtB * 64 + wave * 16 + rl) * 1024;
#pragma unroll
        for (int dt = 0; dt < 4; dt++) {
            O[rowA + dt * 16 + l16] = f2b(oA[dt][r] * invA);
            O[rowB + dt * 16 + l16] = f2b(oB[dt][r] * invB);
        }
    }
}

// ---------------------------------------------------------------------------
extern "C" void kernel_launch(void* const* d_in, const int* in_sizes, int n_in,
                              void* d_out, int out_size, void* d_ws, size_t ws_size,
                              hipStream_t stream) {
    (void)in_sizes; (void)n_in; (void)out_size; (void)ws_size;
    const float* x  = (const float*)d_in[0];
    const float* wq = (const float*)d_in[1];
    const float* wk = (const float*)d_in[2];
    const float* wv = (const float*)d_in[3];
    const float* wo = (const float*)d_in[4];

    const size_t MN = (size_t)4096 * 1024;

    // d_out (16MB): xb (8MB) + wcat (6MB) + rope table (512KB in free tail);
    // all consumed before the final fp32 GEMM overwrites d_out.
    u16* xb   = (u16*)d_out;
    u16* wcat = xb + MN;                    // [3072][1024] = wq|wk|wv rows
    float2* tab = (float2*)(wcat + (size_t)3072 * 1024);
    u16* qbuf = (u16*)d_ws;                 // also attention output
    u16* kbuf = qbuf + MN;
    u16* vbuf = kbuf + MN;
    u16* wob  = vbuf + MN;                  // ws total: 26MB

    cvt_all<<<4096, 256, 0, stream>>>((const float4*)x, (const float4*)wq,
                                      (const float4*)wk, (const float4*)wv,
                                      (const float4*)wo, xb, wcat, wob);
    rope_tab<<<256, 256, 0, stream>>>(tab);
    gemm_qkv<<<256, 512, 0, stream>>>(xb, wcat, qbuf, kbuf, vbuf, tab);
    attn_kernel<<<512, 256, 0, stream>>>(qbuf, kbuf, vbuf, qbuf);
    gemm_tile<2, 16><<<512, 256, 0, stream>>>(qbuf, wob, (float*)d_out);
}